// Round 8
// baseline (138.429 us; speedup 1.0000x reference)
//
#include <hip/hip_runtime.h>
#include <stdint.h>
#include <math.h>

typedef unsigned long long u64;
typedef unsigned int u32;

#define ENT_CAP  8192       // per-row-block capacity (fallback layout only)
#define GCAP     65536      // compact global entry capacity
#define LDSE_CAP 24576      // LDS-staged entry capacity (96 KB)

// ---------------- kernel 1: extract scores + zero counters ----------------
__global__ void k_scores(const float* __restrict__ dets, float* __restrict__ sc,
                         int* __restrict__ cnt, int n) {
    int i = blockIdx.x * blockDim.x + threadIdx.x;
    if (i < n) sc[i] = dets[i * 5 + 4];
    if (i < 129) cnt[i] = 0;      // 128 per-block counters + 1 global total
}

// ---------------- kernel 2a: rank via LDS-staged scores (n <= 8192) ----------------
// 1 block = 64 boxes; 4 waves split the j-range; scores staged once in LDS.
__launch_bounds__(256, 1)
__global__ void k_rank(const float* __restrict__ dets, const float* __restrict__ sc,
                       int* __restrict__ rank,
                       float* __restrict__ sx1, float* __restrict__ sy1,
                       float* __restrict__ sx2, float* __restrict__ sy2,
                       float* __restrict__ sarea, int n) {
    __shared__ float ssc[8192];
    __shared__ int part[4][64];
    int t = threadIdx.x, l = t & 63, wv = t >> 6;
    int n4 = n >> 2;

    const float4* sc4 = (const float4*)sc;
    float4* ssc4 = (float4*)ssc;
    for (int j4 = t; j4 < n4; j4 += 256) ssc4[j4] = sc4[j4];
    for (int j = (n4 << 2) + t; j < n; j += 256) ssc[j] = sc[j];
    __syncthreads();

    int i = blockIdx.x * 64 + l;
    int cnt = 0;
    float si = (i < n) ? ssc[i] : 0.0f;
    if (i < n) {
        for (int j4 = wv; j4 < n4; j4 += 4) {          // uniform LDS broadcast reads
            float4 v = ssc4[j4];
            int j = j4 * 4;
            cnt += (v.x > si) || (v.x == si && (j + 0) < i);
            cnt += (v.y > si) || (v.y == si && (j + 1) < i);
            cnt += (v.z > si) || (v.z == si && (j + 2) < i);
            cnt += (v.w > si) || (v.w == si && (j + 3) < i);
        }
        if (wv == 0) {
            for (int j = n4 << 2; j < n; ++j) {
                float sj = ssc[j];
                cnt += (sj > si) || (sj == si && j < i);
            }
        }
    }
    part[wv][l] = cnt;
    __syncthreads();
    if (wv == 0 && i < n) {
        int r = part[0][l] + part[1][l] + part[2][l] + part[3][l];
        rank[i] = r;
        float x1 = dets[i * 5 + 0], y1 = dets[i * 5 + 1];
        float x2 = dets[i * 5 + 2], y2 = dets[i * 5 + 3];
        sx1[r] = x1; sy1[r] = y1; sx2[r] = x2; sy2[r] = y2;
        sarea[r] = (x2 - x1 + 1.0f) * (y2 - y1 + 1.0f);
    }
}

// ---------------- kernel 2b: fallback rank (any n) — one wave per box ----------------
__global__ void k_rank_big(const float* __restrict__ dets, const float* __restrict__ sc,
                           int* __restrict__ rank,
                           float* __restrict__ sx1, float* __restrict__ sy1,
                           float* __restrict__ sx2, float* __restrict__ sy2,
                           float* __restrict__ sarea, int n) {
    int gid  = blockIdx.x * blockDim.x + threadIdx.x;
    int wave = gid >> 6;
    int lane = threadIdx.x & 63;
    if (wave >= n) return;
    int i = wave;
    float si = sc[i];
    int cnt = 0;
    for (int j = lane; j < n; j += 64) {
        float sj = sc[j];
        cnt += (sj > si) || (sj == si && j < i);
    }
    for (int off = 32; off > 0; off >>= 1) cnt += __shfl_down(cnt, off, 64);
    if (lane == 0) {
        int r = cnt;
        rank[i] = r;
        float x1 = dets[i * 5 + 0], y1 = dets[i * 5 + 1];
        float x2 = dets[i * 5 + 2], y2 = dets[i * 5 + 3];
        sx1[r] = x1; sy1[r] = y1; sx2[r] = x2; sy2[r] = y2;
        sarea[r] = (x2 - x1 + 1.0f) * (y2 - y1 + 1.0f);
    }
}

// ---------------- kernel 3: sparse suppression graph (triangular grid) ----------------
__global__ void k_mask(const float* __restrict__ sx1, const float* __restrict__ sy1,
                       const float* __restrict__ sx2, const float* __restrict__ sy2,
                       const float* __restrict__ sarea, const float* __restrict__ thrp,
                       u64* __restrict__ diag, u64* __restrict__ nzarr,
                       u32* __restrict__ entc, u32* __restrict__ ent2,
                       int* __restrict__ cnt, int n, int nw) {
    int t = blockIdx.x;
    // decode upper-triangular (by, bx), row-major: row by has (nw-by) blocks
    double nn = (double)nw + 0.5;
    int by = (int)(nn - sqrt(nn * nn - 2.0 * (double)t));
    if (by < 0) by = 0; if (by > nw - 1) by = nw - 1;
    while (by + 1 <= nw - 1 && ((by + 1) * nw - ((by + 1) * by) / 2) <= t) ++by;
    while ((by * nw - (by * (by - 1)) / 2) > t) --by;
    int bx = by + (t - (by * nw - (by * (by - 1)) / 2));

    int k  = threadIdx.x;                // 0..63
    int i  = by * 64 + k;                // global row

    __shared__ float cx1[64], cy1[64], cx2[64], cy2[64], ca[64];
    int j0 = bx * 64;
    cx1[k] = sx1[j0 + k]; cy1[k] = sy1[j0 + k];
    cx2[k] = sx2[j0 + k]; cy2[k] = sy2[j0 + k];
    ca[k]  = sarea[j0 + k];
    __syncthreads();

    float x1 = sx1[i], y1 = sy1[i], x2 = sx2[i], y2 = sy2[i], ar = sarea[i];
    float thr = *thrp;
    u64 word = 0ULL;
    #pragma unroll 8
    for (int jj = 0; jj < 64; ++jj) {
        float xx1 = fmaxf(x1, cx1[jj]);
        float yy1 = fmaxf(y1, cy1[jj]);
        float xx2 = fminf(x2, cx2[jj]);
        float yy2 = fminf(y2, cy2[jj]);
        float w = fmaxf(xx2 - xx1 + 1.0f, 0.0f);
        float h = fmaxf(yy2 - yy1 + 1.0f, 0.0f);
        float inter = w * h;
        float iou = inter / (ar + ca[jj] - inter);   // same op order as reference
        word |= ((u64)(iou > thr)) << jj;
    }

    if (bx == by) {
        word &= ~((2ULL << k) - 1ULL);   // keep only j > i
        diag[i] = word;
        u64 bal = __ballot(word != 0ULL);
        if (k == 0) nzarr[by] = bal;     // free nz summary for k_scan
        return;
    }
    if (__ballot(word != 0ULL) == 0ULL) return;   // whole block conflict-free
    int pc = __popcll(word);
    if (pc) {
        int base2 = atomicAdd(&cnt[by], pc);       // per-block (fallback layout)
        int baseg = atomicAdd(&cnt[128], pc);      // compact global array
        u64 ww = word;
        int x = 0;
        while (ww) {
            int jj = __builtin_ctzll(ww); ww &= ww - 1;
            int j = j0 + jj;
            if (base2 + x < ENT_CAP)
                ent2[(size_t)by * ENT_CAP + base2 + x] = ((u32)k << 16) | (u32)j;
            if (n <= 8192 && baseg + x < GCAP)
                entc[baseg + x] = ((u32)by << 19) | ((u32)k << 13) | (u32)j;
            ++x;
        }
    }
}

// ---------------- helper: readlane of a u64 (uniform runtime lane index) ----------------
__device__ __forceinline__ u64 readlane_u64(u64 v, int lane) {
    unsigned lo = (unsigned)__builtin_amdgcn_readlane((int)(v & 0xffffffffu), lane);
    unsigned hi = (unsigned)__builtin_amdgcn_readlane((int)(v >> 32), lane);
    return ((u64)hi << 32) | lo;
}

// ---------------- kernel 4: sparse greedy scan — single wave, NO globals in hot loop ----------------
__launch_bounds__(64, 1)
__global__ void k_scan(const u64* __restrict__ diag, const u64* __restrict__ nzarr,
                       const u32* __restrict__ entc, const u32* __restrict__ ent2,
                       const int* __restrict__ cnt, u64* __restrict__ remv,
                       int n, int nw) {
    extern __shared__ char smem[];
    u64* lds_remv = (u64*)smem;                 // 128 u64
    int* lds_cur  = (int*)(smem + 1024);        // 128 int
    u32* lds_ent  = (u32*)(smem + 1536);        // LDSE_CAP u32

    int lane = threadIdx.x;
    lds_remv[lane] = 0ULL;
    lds_remv[64 + lane] = 0ULL;

    int c0 = cnt[lane];
    int c1 = cnt[64 + lane];
    int S  = cnt[128];
    u64 nz0 = (lane < nw)      ? nzarr[lane]      : 0ULL;
    u64 nz1 = (64 + lane < nw) ? nzarr[64 + lane] : 0ULL;

    // exclusive prefix offsets over 128 counts (wave-parallel scan, no memory)
    int s0 = c0;
    #pragma unroll
    for (int d = 1; d < 64; d <<= 1) { int tv = __shfl_up(s0, d, 64); if (lane >= d) s0 += tv; }
    int tot0 = __builtin_amdgcn_readlane(s0, 63);
    int s1 = c1;
    #pragma unroll
    for (int d = 1; d < 64; d <<= 1) { int tv = __shfl_up(s1, d, 64); if (lane >= d) s1 += tv; }
    int o0 = s0 - c0;
    int o1 = tot0 + s1 - c1;

    bool fast = (S <= LDSE_CAP) && (n <= 8192);

    if (fast) {
        lds_cur[lane] = o0;
        lds_cur[64 + lane] = o1;
        // stage all S compact entries into LDS, bucketed by block
        for (int g0 = 0; g0 < S; g0 += 1024) {
            int base = g0 + lane * 16;
            uint4 v0 = *(const uint4*)(entc + base);
            uint4 v1 = *(const uint4*)(entc + base + 4);
            uint4 v2 = *(const uint4*)(entc + base + 8);
            uint4 v3 = *(const uint4*)(entc + base + 12);
            u32 ee[16] = { v0.x, v0.y, v0.z, v0.w, v1.x, v1.y, v1.z, v1.w,
                           v2.x, v2.y, v2.z, v2.w, v3.x, v3.y, v3.z, v3.w };
            #pragma unroll
            for (int u = 0; u < 16; ++u) {
                if (base + u < S) {
                    u32 e = ee[u];
                    int b = e >> 19;
                    int pos = atomicAdd(&lds_cur[b], 1);
                    lds_ent[pos] = e;
                }
            }
        }
    }

    for (int b = 0; b < nw; ++b) {
        int sel = b & 63;
        int cb  = __builtin_amdgcn_readlane((b < 64) ? c0 : c1, sel);
        u64 nzb = readlane_u64((b < 64) ? nz0 : nz1, sel);
        if ((nzb | (u64)(u32)cb) == 0ULL) continue;     // pure-register skip

        u64 w = lds_remv[b];               // sees all prior atomicOrs (same wave, in-order LDS)
        if (nzb & ~w) {
            u64 avail = ~w & nzb;
            while (avail) {                // ascending greedy over alive conflicting rows
                int k = __builtin_ctzll(avail);
                w |= diag[(size_t)b * 64 + k];          // uniform L2 load — rare path
                avail &= ~(w | (1ULL << k));
            }
            if (lane == 0) lds_remv[b] = w;
        }
        int ob = __builtin_amdgcn_readlane((b < 64) ? o0 : o1, sel);
        if (fast) {
            for (int idx = lane; idx < cb; idx += 64) {
                u32 e = lds_ent[ob + idx];
                int k = (e >> 13) & 63, j = e & 8191;
                if (!((w >> k) & 1ULL)) atomicOr(&lds_remv[j >> 6], 1ULL << (j & 63));
            }
        } else {
            int cbl = (cb < ENT_CAP) ? cb : ENT_CAP;
            for (int idx = lane; idx < cbl; idx += 64) {
                u32 e = ent2[(size_t)b * ENT_CAP + idx];
                int k = e >> 16, j = e & 0xffff;
                if (!((w >> k) & 1ULL)) atomicOr(&lds_remv[j >> 6], 1ULL << (j & 63));
            }
        }
    }

    if (lane < nw) remv[lane] = lds_remv[lane];
    if (64 + lane < nw) remv[64 + lane] = lds_remv[64 + lane];
}

// ---------------- kernel 5: write output ----------------
__global__ void k_out(const float* __restrict__ dets, const int* __restrict__ rank,
                      const u64* __restrict__ remv, float* __restrict__ out, int n) {
    int idx = blockIdx.x * blockDim.x + threadIdx.x;
    if (idx >= n * 5) return;
    int i = idx / 5;
    int r = rank[i];
    u64 w = remv[r >> 6];
    float keep = ((w >> (r & 63)) & 1ULL) ? 0.0f : 1.0f;
    out[idx] = dets[idx] * keep;
}

extern "C" void kernel_launch(void* const* d_in, const int* in_sizes, int n_in,
                              void* d_out, int out_size, void* d_ws, size_t ws_size,
                              hipStream_t stream) {
    const float* dets = (const float*)d_in[0];
    const float* thrp = (const float*)d_in[1];
    int n  = in_sizes[0] / 5;
    int nw = (n + 63) / 64;

    char* ws = (char*)d_ws;
    size_t off = 0;
    auto carve = [&](size_t bytes) { char* p = ws + off; off = (off + bytes + 255) & ~(size_t)255; return p; };
    u64* diag  = (u64*)carve((size_t)n * sizeof(u64));
    u64* nzarr = (u64*)carve(128 * sizeof(u64));
    u32* entc  = (u32*)carve((size_t)GCAP * sizeof(u32));
    u32* ent2  = (u32*)carve((size_t)128 * ENT_CAP * sizeof(u32));
    int* cnt   = (int*)carve(129 * sizeof(int));
    float* sc    = (float*)carve((size_t)n * sizeof(float));
    int*   rank  = (int*)  carve((size_t)n * sizeof(int));
    float* sx1   = (float*)carve((size_t)n * sizeof(float));
    float* sy1   = (float*)carve((size_t)n * sizeof(float));
    float* sx2   = (float*)carve((size_t)n * sizeof(float));
    float* sy2   = (float*)carve((size_t)n * sizeof(float));
    float* sarea = (float*)carve((size_t)n * sizeof(float));
    u64* remv    = (u64*)  carve((size_t)nw * sizeof(u64));

    float* out = (float*)d_out;

    int tri = nw * (nw + 1) / 2;
    int scan_lds = 1024 + 512 + LDSE_CAP * 4;

    k_scores<<<(n + 255) / 256, 256, 0, stream>>>(dets, sc, cnt, n);
    if (n <= 8192)
        k_rank<<<nw, 256, 0, stream>>>(dets, sc, rank, sx1, sy1, sx2, sy2, sarea, n);
    else
        k_rank_big<<<(n * 64 + 255) / 256, 256, 0, stream>>>(dets, sc, rank, sx1, sy1, sx2, sy2, sarea, n);
    k_mask<<<tri, 64, 0, stream>>>(sx1, sy1, sx2, sy2, sarea, thrp, diag, nzarr, entc, ent2, cnt, n, nw);
    k_scan<<<1, 64, scan_lds, stream>>>(diag, nzarr, entc, ent2, cnt, remv, n, nw);
    k_out<<<(n * 5 + 255) / 256, 256, 0, stream>>>(dets, rank, remv, out, n);
}

// Round 9
// 91.937 us; speedup vs baseline: 1.5057x; 1.5057x over previous
//
#include <hip/hip_runtime.h>
#include <stdint.h>
#include <math.h>

typedef unsigned long long u64;
typedef unsigned int u32;

#define ENT_CAP  8192       // per-row-block capacity (fallback layout only)
#define GCAP     65536      // compact global entry capacity
#define LDSE_CAP 24576      // LDS-staged entry capacity (96 KB)

// ---------------- kernel 1: extract scores + zero counters ----------------
__global__ void k_scores(const float* __restrict__ dets, float* __restrict__ sc,
                         int* __restrict__ cnt, int n) {
    int i = blockIdx.x * blockDim.x + threadIdx.x;
    if (i < n) sc[i] = dets[i * 5 + 4];
    if (i < 129) cnt[i] = 0;      // 128 per-block counters + 1 global total
}

// ---------------- kernel 2: rank (counting sort) + scatter sorted boxes ----------------
// one wave (64 lanes) per box i; float4-vectorized score reads. 8192 waves ->
// full TLP, global-load latency hidden by occupancy (do NOT LDS-stage this:
// round-7 regression showed 1-wave/SIMD LDS broadcast chain is 3x slower).
__global__ void k_rank(const float* __restrict__ dets, const float* __restrict__ sc,
                       int* __restrict__ rank,
                       float* __restrict__ sx1, float* __restrict__ sy1,
                       float* __restrict__ sx2, float* __restrict__ sy2,
                       float* __restrict__ sarea, int n) {
    int gid  = blockIdx.x * blockDim.x + threadIdx.x;
    int wave = gid >> 6;
    int lane = threadIdx.x & 63;
    if (wave >= n) return;
    int i = wave;
    float si = sc[i];
    int cnt = 0;
    int n4 = n >> 2;
    const float4* sc4 = (const float4*)sc;
    for (int j4 = lane; j4 < n4; j4 += 64) {
        float4 v = sc4[j4];
        int j = j4 * 4;
        cnt += (v.x > si) || (v.x == si && (j + 0) < i);
        cnt += (v.y > si) || (v.y == si && (j + 1) < i);
        cnt += (v.z > si) || (v.z == si && (j + 2) < i);
        cnt += (v.w > si) || (v.w == si && (j + 3) < i);
    }
    for (int j = (n4 << 2) + lane; j < n; j += 64) {   // tail (n%4 != 0)
        float sj = sc[j];
        cnt += (sj > si) || (sj == si && j < i);
    }
    for (int off = 32; off > 0; off >>= 1) cnt += __shfl_down(cnt, off, 64);
    if (lane == 0) {
        int r = cnt;
        rank[i] = r;
        float x1 = dets[i * 5 + 0], y1 = dets[i * 5 + 1];
        float x2 = dets[i * 5 + 2], y2 = dets[i * 5 + 3];
        sx1[r] = x1; sy1[r] = y1; sx2[r] = x2; sy2[r] = y2;
        sarea[r] = (x2 - x1 + 1.0f) * (y2 - y1 + 1.0f);
    }
}

// ---------------- kernel 3: sparse suppression graph (triangular grid) ----------------
__global__ void k_mask(const float* __restrict__ sx1, const float* __restrict__ sy1,
                       const float* __restrict__ sx2, const float* __restrict__ sy2,
                       const float* __restrict__ sarea, const float* __restrict__ thrp,
                       u64* __restrict__ diag, u64* __restrict__ nzarr,
                       u32* __restrict__ entc, u32* __restrict__ ent2,
                       int* __restrict__ cnt, int n, int nw) {
    int t = blockIdx.x;
    // decode upper-triangular (by, bx), row-major: row by has (nw-by) blocks
    double nn = (double)nw + 0.5;
    int by = (int)(nn - sqrt(nn * nn - 2.0 * (double)t));
    if (by < 0) by = 0; if (by > nw - 1) by = nw - 1;
    while (by + 1 <= nw - 1 && ((by + 1) * nw - ((by + 1) * by) / 2) <= t) ++by;
    while ((by * nw - (by * (by - 1)) / 2) > t) --by;
    int bx = by + (t - (by * nw - (by * (by - 1)) / 2));

    int k  = threadIdx.x;                // 0..63
    int i  = by * 64 + k;                // global row

    __shared__ float cx1[64], cy1[64], cx2[64], cy2[64], ca[64];
    int j0 = bx * 64;
    cx1[k] = sx1[j0 + k]; cy1[k] = sy1[j0 + k];
    cx2[k] = sx2[j0 + k]; cy2[k] = sy2[j0 + k];
    ca[k]  = sarea[j0 + k];
    __syncthreads();

    float x1 = sx1[i], y1 = sy1[i], x2 = sx2[i], y2 = sy2[i], ar = sarea[i];
    float thr = *thrp;
    u64 word = 0ULL;
    #pragma unroll 8
    for (int jj = 0; jj < 64; ++jj) {
        float xx1 = fmaxf(x1, cx1[jj]);
        float yy1 = fmaxf(y1, cy1[jj]);
        float xx2 = fminf(x2, cx2[jj]);
        float yy2 = fminf(y2, cy2[jj]);
        float w = fmaxf(xx2 - xx1 + 1.0f, 0.0f);
        float h = fmaxf(yy2 - yy1 + 1.0f, 0.0f);
        float inter = w * h;
        float iou = inter / (ar + ca[jj] - inter);   // same op order as reference
        word |= ((u64)(iou > thr)) << jj;
    }

    if (bx == by) {
        word &= ~((2ULL << k) - 1ULL);   // keep only j > i
        diag[i] = word;
        u64 bal = __ballot(word != 0ULL);
        if (k == 0) nzarr[by] = bal;     // free nz summary for k_scan
        return;
    }
    if (__ballot(word != 0ULL) == 0ULL) return;   // whole block conflict-free
    int pc = __popcll(word);
    if (pc) {
        int base2 = atomicAdd(&cnt[by], pc);       // per-block (fallback layout)
        int baseg = atomicAdd(&cnt[128], pc);      // compact global array
        u64 ww = word;
        int x = 0;
        while (ww) {
            int jj = __builtin_ctzll(ww); ww &= ww - 1;
            int j = j0 + jj;
            if (base2 + x < ENT_CAP)
                ent2[(size_t)by * ENT_CAP + base2 + x] = ((u32)k << 16) | (u32)j;
            if (n <= 8192 && baseg + x < GCAP)
                entc[baseg + x] = ((u32)by << 19) | ((u32)k << 13) | (u32)j;
            ++x;
        }
    }
}

// ---------------- helper: readlane of a u64 (uniform runtime lane index) ----------------
__device__ __forceinline__ u64 readlane_u64(u64 v, int lane) {
    unsigned lo = (unsigned)__builtin_amdgcn_readlane((int)(v & 0xffffffffu), lane);
    unsigned hi = (unsigned)__builtin_amdgcn_readlane((int)(v >> 32), lane);
    return ((u64)hi << 32) | lo;
}

// ---------------- kernel 4: sparse greedy scan — single wave, NO globals in hot loop ----------------
__launch_bounds__(64, 1)
__global__ void k_scan(const u64* __restrict__ diag, const u64* __restrict__ nzarr,
                       const u32* __restrict__ entc, const u32* __restrict__ ent2,
                       const int* __restrict__ cnt, u64* __restrict__ remv,
                       int n, int nw) {
    extern __shared__ char smem[];
    u64* lds_remv = (u64*)smem;                 // 128 u64
    int* lds_cur  = (int*)(smem + 1024);        // 128 int
    u32* lds_ent  = (u32*)(smem + 1536);        // LDSE_CAP u32

    int lane = threadIdx.x;
    lds_remv[lane] = 0ULL;
    lds_remv[64 + lane] = 0ULL;

    int c0 = cnt[lane];
    int c1 = cnt[64 + lane];
    int S  = cnt[128];
    u64 nz0 = (lane < nw)      ? nzarr[lane]      : 0ULL;
    u64 nz1 = (64 + lane < nw) ? nzarr[64 + lane] : 0ULL;

    // exclusive prefix offsets over 128 counts (wave-parallel scan, no memory)
    int s0 = c0;
    #pragma unroll
    for (int d = 1; d < 64; d <<= 1) { int tv = __shfl_up(s0, d, 64); if (lane >= d) s0 += tv; }
    int tot0 = __builtin_amdgcn_readlane(s0, 63);
    int s1 = c1;
    #pragma unroll
    for (int d = 1; d < 64; d <<= 1) { int tv = __shfl_up(s1, d, 64); if (lane >= d) s1 += tv; }
    int o0 = s0 - c0;
    int o1 = tot0 + s1 - c1;

    bool fast = (S <= LDSE_CAP) && (n <= 8192);

    if (fast) {
        lds_cur[lane] = o0;
        lds_cur[64 + lane] = o1;
        // stage all S compact entries into LDS, bucketed by block
        for (int g0 = 0; g0 < S; g0 += 1024) {
            int base = g0 + lane * 16;
            uint4 v0 = *(const uint4*)(entc + base);
            uint4 v1 = *(const uint4*)(entc + base + 4);
            uint4 v2 = *(const uint4*)(entc + base + 8);
            uint4 v3 = *(const uint4*)(entc + base + 12);
            u32 ee[16] = { v0.x, v0.y, v0.z, v0.w, v1.x, v1.y, v1.z, v1.w,
                           v2.x, v2.y, v2.z, v2.w, v3.x, v3.y, v3.z, v3.w };
            #pragma unroll
            for (int u = 0; u < 16; ++u) {
                if (base + u < S) {
                    u32 e = ee[u];
                    int b = e >> 19;
                    int pos = atomicAdd(&lds_cur[b], 1);
                    lds_ent[pos] = e;
                }
            }
        }
    }

    for (int b = 0; b < nw; ++b) {
        int sel = b & 63;
        int cb  = __builtin_amdgcn_readlane((b < 64) ? c0 : c1, sel);
        u64 nzb = readlane_u64((b < 64) ? nz0 : nz1, sel);
        if ((nzb | (u64)(u32)cb) == 0ULL) continue;     // pure-register skip

        u64 w = lds_remv[b];               // sees all prior atomicOrs (same wave, in-order LDS)
        if (nzb & ~w) {
            u64 avail = ~w & nzb;
            while (avail) {                // ascending greedy over alive conflicting rows
                int k = __builtin_ctzll(avail);
                w |= diag[(size_t)b * 64 + k];          // uniform L2 load — rare path
                avail &= ~(w | (1ULL << k));
            }
            if (lane == 0) lds_remv[b] = w;
        }
        int ob = __builtin_amdgcn_readlane((b < 64) ? o0 : o1, sel);
        if (fast) {
            for (int idx = lane; idx < cb; idx += 64) {
                u32 e = lds_ent[ob + idx];
                int k = (e >> 13) & 63, j = e & 8191;
                if (!((w >> k) & 1ULL)) atomicOr(&lds_remv[j >> 6], 1ULL << (j & 63));
            }
        } else {
            int cbl = (cb < ENT_CAP) ? cb : ENT_CAP;
            for (int idx = lane; idx < cbl; idx += 64) {
                u32 e = ent2[(size_t)b * ENT_CAP + idx];
                int k = e >> 16, j = e & 0xffff;
                if (!((w >> k) & 1ULL)) atomicOr(&lds_remv[j >> 6], 1ULL << (j & 63));
            }
        }
    }

    if (lane < nw) remv[lane] = lds_remv[lane];
    if (64 + lane < nw) remv[64 + lane] = lds_remv[64 + lane];
}

// ---------------- kernel 5: write output ----------------
__global__ void k_out(const float* __restrict__ dets, const int* __restrict__ rank,
                      const u64* __restrict__ remv, float* __restrict__ out, int n) {
    int idx = blockIdx.x * blockDim.x + threadIdx.x;
    if (idx >= n * 5) return;
    int i = idx / 5;
    int r = rank[i];
    u64 w = remv[r >> 6];
    float keep = ((w >> (r & 63)) & 1ULL) ? 0.0f : 1.0f;
    out[idx] = dets[idx] * keep;
}

extern "C" void kernel_launch(void* const* d_in, const int* in_sizes, int n_in,
                              void* d_out, int out_size, void* d_ws, size_t ws_size,
                              hipStream_t stream) {
    const float* dets = (const float*)d_in[0];
    const float* thrp = (const float*)d_in[1];
    int n  = in_sizes[0] / 5;
    int nw = (n + 63) / 64;

    char* ws = (char*)d_ws;
    size_t off = 0;
    auto carve = [&](size_t bytes) { char* p = ws + off; off = (off + bytes + 255) & ~(size_t)255; return p; };
    u64* diag  = (u64*)carve((size_t)n * sizeof(u64));
    u64* nzarr = (u64*)carve(128 * sizeof(u64));
    u32* entc  = (u32*)carve((size_t)GCAP * sizeof(u32));
    u32* ent2  = (u32*)carve((size_t)128 * ENT_CAP * sizeof(u32));
    int* cnt   = (int*)carve(129 * sizeof(int));
    float* sc    = (float*)carve((size_t)n * sizeof(float));
    int*   rank  = (int*)  carve((size_t)n * sizeof(int));
    float* sx1   = (float*)carve((size_t)n * sizeof(float));
    float* sy1   = (float*)carve((size_t)n * sizeof(float));
    float* sx2   = (float*)carve((size_t)n * sizeof(float));
    float* sy2   = (float*)carve((size_t)n * sizeof(float));
    float* sarea = (float*)carve((size_t)n * sizeof(float));
    u64* remv    = (u64*)  carve((size_t)nw * sizeof(u64));

    float* out = (float*)d_out;

    int tri = nw * (nw + 1) / 2;
    int scan_lds = 1024 + 512 + LDSE_CAP * 4;

    k_scores<<<(n + 255) / 256, 256, 0, stream>>>(dets, sc, cnt, n);
    k_rank<<<(n * 64 + 255) / 256, 256, 0, stream>>>(dets, sc, rank, sx1, sy1, sx2, sy2, sarea, n);
    k_mask<<<tri, 64, 0, stream>>>(sx1, sy1, sx2, sy2, sarea, thrp, diag, nzarr, entc, ent2, cnt, n, nw);
    k_scan<<<1, 64, scan_lds, stream>>>(diag, nzarr, entc, ent2, cnt, remv, n, nw);
    k_out<<<(n * 5 + 255) / 256, 256, 0, stream>>>(dets, rank, remv, out, n);
}